// Round 3
// baseline (757.653 us; speedup 1.0000x reference)
//
#include <hip/hip_runtime.h>
#include <hip/hip_bf16.h>

#define B_ 16
#define T_ 4096
#define TREG 4088
#define D_ 768
#define NSS 8
#define INNER_ 192
#define NK 1536

typedef unsigned int u32;
typedef unsigned short u16;
typedef __attribute__((ext_vector_type(8))) short bf16x8;
typedef __attribute__((ext_vector_type(4))) float f32x4;

__device__ __forceinline__ u16 f2bf(float f) {
  union { __hip_bfloat16 h; u16 u; } cv;
  cv.h = __float2bfloat16(f);
  return cv.u;
}

// ---------------- K0: Wv (768x768, k-major) -> WvT bf16 (n-major) ----------
__global__ __launch_bounds__(256) void k_wvt(const float* __restrict__ Wv,
                                             u16* __restrict__ wvT) {
  __shared__ float tile[16][17];
  int tx = threadIdx.x & 15, ty = threadIdx.x >> 4;
  int nb = blockIdx.x * 16, kb = blockIdx.y * 16;
  tile[ty][tx] = Wv[(size_t)(kb + ty) * D_ + nb + tx];
  __syncthreads();
  wvT[(size_t)(nb + ty) * D_ + kb + tx] = f2bf(tile[tx][ty]);
}

// ---------------- K1: cast x -> bf16 (optional) + per-batch column sums ----
// grid (T_/32=128, B_), 192 thr; 32 tokens per block.
template <bool CONV>
__global__ __launch_bounds__(192) void k_conv_mean(const float* __restrict__ x,
                                                   u16* __restrict__ xb,
                                                   float* __restrict__ means) {
  int b = blockIdx.y, tc = blockIdx.x, tid = threadIdx.x;
  const float4* xp = (const float4*)(x + (size_t)(b * T_ + tc * 32) * D_) + tid;
  ushort4* op = nullptr;
  if (CONV) op = ((ushort4*)(xb + (size_t)(b * T_ + tc * 32) * D_)) + tid;
  float s0 = 0, s1 = 0, s2 = 0, s3 = 0;
  int tbase = tc * 32;
#pragma unroll 4
  for (int tt = 0; tt < 32; ++tt) {
    float4 v = xp[(size_t)tt * 192];
    if (CONV) {
      ushort4 o;
      o.x = f2bf(v.x); o.y = f2bf(v.y); o.z = f2bf(v.z); o.w = f2bf(v.w);
      op[(size_t)tt * 192] = o;
    }
    if (tbase + tt < TREG) { s0 += v.x; s1 += v.y; s2 += v.z; s3 += v.w; }
  }
  float* m = means + (size_t)b * D_ + tid * 4;
  atomicAdd(m + 0, s0); atomicAdd(m + 1, s1);
  atomicAdd(m + 2, s2); atomicAdd(m + 3, s3);
}

// ---------------- K2a: ssu[b][n] = mean(reg)[b] @ Wk + bk  -----------------
__global__ __launch_bounds__(256) void k_ssu(const float* __restrict__ means,
                                             const float* __restrict__ Wk,
                                             const float* __restrict__ bk,
                                             float* __restrict__ ssu) {
  int b = blockIdx.y, tid = threadIdx.x;
  int n = blockIdx.x * 256 + tid;
  __shared__ float mv[D_];
  for (int d = tid; d < D_; d += 256)
    mv[d] = means[(size_t)b * D_ + d] * (1.0f / TREG);
  __syncthreads();
  float a = bk[n];
#pragma unroll 8
  for (int d = 0; d < D_; ++d) a += mv[d] * Wk[(size_t)d * NK + n];
  ssu[(size_t)b * NK + n] = a;
}

// ---------------- K2b: new_ss rows + qb; grid (NSS, B_) --------------------
__global__ __launch_bounds__(256) void k_nss(
    const float* __restrict__ x, const float* __restrict__ ssu,
    const float* __restrict__ Wss, const float* __restrict__ bss,
    const float* __restrict__ bq, float* __restrict__ out,
    float* __restrict__ nssf, u16* __restrict__ nssT, float* __restrict__ qb) {
  int s = blockIdx.x, b = blockIdx.y, tid = threadIdx.x;
  __shared__ float su[INNER_];
  __shared__ float qred[4];
  if (tid < INNER_) su[tid] = ssu[(size_t)b * NK + s * INNER_ + tid];
  __syncthreads();
  size_t xr = (size_t)(b * T_ + TREG + s) * D_;
  float a0 = x[xr + tid]       + bss[tid];
  float a1 = x[xr + tid + 256] + bss[tid + 256];
  float a2 = x[xr + tid + 512] + bss[tid + 512];
#pragma unroll 4
  for (int i = 0; i < INNER_; ++i) {
    float sv = su[i];
    const float* wr = Wss + (size_t)i * D_ + tid;
    a0 += sv * wr[0]; a1 += sv * wr[256]; a2 += sv * wr[512];
  }
  out[xr + tid] = a0; out[xr + tid + 256] = a1; out[xr + tid + 512] = a2;
  size_t nb = (size_t)(b * NSS + s) * D_;
  nssf[nb + tid] = a0; nssf[nb + tid + 256] = a1; nssf[nb + tid + 512] = a2;
  size_t tb = (size_t)b * D_;
  nssT[(tb + tid) * NSS + s] = f2bf(a0);
  nssT[(tb + tid + 256) * NSS + s] = f2bf(a1);
  nssT[(tb + tid + 512) * NSS + s] = f2bf(a2);
  float q = bq[tid] * a0 + bq[tid + 256] * a1 + bq[tid + 512] * a2;
#pragma unroll
  for (int o = 1; o < 64; o <<= 1) q += __shfl_xor(q, o, 64);
  if ((tid & 63) == 0) qred[tid >> 6] = q;
  __syncthreads();
  if (tid == 0) qb[b * NSS + s] = qred[0] + qred[1] + qred[2] + qred[3];
}

// ---------------- K2c: Wqs[b] = Wq @ new_ss[b]^T -> bf16 [b][8][768] -------
__global__ __launch_bounds__(256) void k_wqs(const float* __restrict__ Wq,
                                             const float* __restrict__ nssf,
                                             u16* __restrict__ wqsT) {
  __shared__ float nss[NSS * (D_ + 4)];
  int b = blockIdx.y, tid = threadIdx.x;
  int o = blockIdx.x * 256 + tid;
  int j = o >> 3, s = o & 7;
  for (int i = tid; i < NSS * D_; i += 256) {
    int s2 = i / D_, d2 = i - s2 * D_;
    nss[s2 * (D_ + 4) + d2] = nssf[(size_t)b * NSS * D_ + i];
  }
  __syncthreads();
  const float* wr = Wq + (size_t)j * D_;
  const float* nr = nss + s * (D_ + 4);
  float a = 0;
#pragma unroll 8
  for (int d = 0; d < D_; ++d) a += wr[d] * nr[d];
  wqsT[((size_t)b * NSS + s) * D_ + j] = f2bf(a);
}

// helper: load a K=32 MFMA A/B fragment (8 bf16) straight from global.
template <bool BF>
__device__ __forceinline__ bf16x8 ldfrag(const u16* pb, const float* pf,
                                         size_t off) {
  if constexpr (BF) {
    return *(const bf16x8*)(pb + off);
  } else {
    float4 f0 = *(const float4*)(pf + off);
    float4 f1 = *(const float4*)(pf + off + 4);
    bf16x8 r;
    r[0] = (short)f2bf(f0.x); r[1] = (short)f2bf(f0.y);
    r[2] = (short)f2bf(f0.z); r[3] = (short)f2bf(f0.w);
    r[4] = (short)f2bf(f1.x); r[5] = (short)f2bf(f1.y);
    r[6] = (short)f2bf(f1.z); r[7] = (short)f2bf(f1.w);
    return r;
  }
}

// ---------------- K3: fused x_v GEMM + sim + softmax + upd + ReLU ----------
// Barrier-free K-loop: A/B fragments loaded global->VGPR (dwordx4), register
// double-buffered. LDS holds only Wqs (8x776) + 16KB epilogue overlay.
// Grid: 3072 1D, XCD-swizzled so each (t,b) A-tile is owned by one XCD.
template <bool ABF16>
__global__ __launch_bounds__(256, 3) void k_main(
    const u16* __restrict__ xb, const float* __restrict__ xf,
    const u16* __restrict__ wvT, const u16* __restrict__ wqsT,
    const u16* __restrict__ nssTg, const float* __restrict__ qb,
    const float* __restrict__ bv, float* __restrict__ out) {
  __shared__ uint4 ldsv[1024];                 // 16 KB
  u16* lds = (u16*)ldsv;
  u16* Ws = lds;                               // Wqs: 8 rows x 776 bf16

  const int tid = threadIdx.x;
  // XCD-aware decode: g = xcd + 8*(pair*6 + nblk); pid = pair*8 + xcd.
  const int g = blockIdx.x;
  const int xcd = g & 7;
  const int li = g >> 3;            // 0..383
  const int nblk = li % 6;
  const int pair = li / 6;          // 0..63
  const int pid = pair * 8 + xcd;   // 0..511 unique (t,b)
  const int t0 = (pid & 31) * 128;
  const int b = pid >> 5;
  const int n0 = nblk * 128;

  const int wave = tid >> 6, lane = tid & 63;
  const int wy = wave >> 1, wx = wave & 1;
  const int lr = lane & 15, lq = lane >> 4;

  // stage Wqs rows (row stride 776 to dodge bank conflicts)
  if (tid < 96) {
    for (int s = 0; s < 8; ++s)
      ((uint4*)(Ws + s * 776))[tid] =
          ((const uint4*)(wqsT + ((size_t)b * NSS + s) * D_))[tid];
  }
  __syncthreads();

  f32x4 acc[4][4];
  f32x4 sacc[4];
#pragma unroll
  for (int i = 0; i < 4; ++i) {
    sacc[i] = f32x4{0.f, 0.f, 0.f, 0.f};
#pragma unroll
    for (int j = 0; j < 4; ++j) acc[i][j] = f32x4{0.f, 0.f, 0.f, 0.f};
  }

  // per-lane fragment bases
  const u16* Ab = ABF16 ? xb + (size_t)(b * T_ + t0 + wy * 64) * D_ + lq * 8
                        : nullptr;
  const float* Af = ABF16 ? nullptr
                          : xf + (size_t)(b * T_ + t0 + wy * 64) * D_ + lq * 8;
  const u16* Bb = wvT + (size_t)(n0 + wx * 64) * D_ + lq * 8;

  bf16x8 aC[4], bC[4], aN[4], bN[4];
#pragma unroll
  for (int mt = 0; mt < 4; ++mt)
    aC[mt] = ldfrag<ABF16>(Ab, Af, (size_t)(mt * 16 + lr) * D_);
#pragma unroll
  for (int nt = 0; nt < 4; ++nt)
    bC[nt] = *(const bf16x8*)(Bb + (size_t)(nt * 16 + lr) * D_);

#pragma unroll
  for (int kk = 0; kk < 24; ++kk) {
    const int k0 = kk * 32;
    if (kk < 23) {
#pragma unroll
      for (int mt = 0; mt < 4; ++mt)
        aN[mt] = ldfrag<ABF16>(Ab, Af, (size_t)(mt * 16 + lr) * D_ + k0 + 32);
#pragma unroll
      for (int nt = 0; nt < 4; ++nt)
        bN[nt] = *(const bf16x8*)(Bb + (size_t)(nt * 16 + lr) * D_ + k0 + 32);
    }
    bf16x8 qf = *(const bf16x8*)(Ws + (lr & 7) * 776 + k0 + lq * 8);
#pragma unroll
    for (int mt = 0; mt < 4; ++mt) {
#pragma unroll
      for (int nt = 0; nt < 4; ++nt)
        acc[mt][nt] = __builtin_amdgcn_mfma_f32_16x16x32_bf16(
            aC[mt], bC[nt], acc[mt][nt], 0, 0, 0);
      sacc[mt] = __builtin_amdgcn_mfma_f32_16x16x32_bf16(
          aC[mt], qf, sacc[mt], 0, 0, 0);
    }
#pragma unroll
    for (int i = 0; i < 4; ++i) { aC[i] = aN[i]; bC[i] = bN[i]; }
  }

  // ---- epilogue: overlay anb(128x32) + nsl(128x32) over Ws region
  __syncthreads();                 // all waves done with Ws
  u16* anb = lds;
  u16* nsl = lds + 4096;
  {
    uint4 z; z.x = z.y = z.z = z.w = 0;
    if (tid < 128) {
      uint4 v = *(const uint4*)(nssTg + ((size_t)b * D_ + n0 + tid) * NSS);
      *(uint4*)(nsl + tid * 32) = v;
      *(uint4*)(nsl + tid * 32 + 8) = z;
      *(uint4*)(nsl + tid * 32 + 16) = z;
      *(uint4*)(nsl + tid * 32 + 24) = z;
    } else {
      int r = tid - 128;
      *(uint4*)(anb + r * 32 + 8) = z;
      *(uint4*)(anb + r * 32 + 16) = z;
      *(uint4*)(anb + r * 32 + 24) = z;
    }
  }
  __syncthreads();

  const float scale = 0.03608439182435161f;  // 1/sqrt(768)
  const float qbias = (lr < 8) ? qb[b * NSS + lr] : 0.f;
#pragma unroll
  for (int mt = 0; mt < 4; ++mt) {
    f32x4 s4 = sacc[mt];
#pragma unroll
    for (int r = 0; r < 4; ++r) {
      float v = (lr < 8) ? (s4[r] + qbias) * scale : -1.0e30f;
      float mx = v;
      mx = fmaxf(mx, __shfl_xor(mx, 1, 16));
      mx = fmaxf(mx, __shfl_xor(mx, 2, 16));
      mx = fmaxf(mx, __shfl_xor(mx, 4, 16));
      float e = (lr < 8) ? __expf(v - mx) : 0.f;
      float sm = e;
      sm += __shfl_xor(sm, 1, 16);
      sm += __shfl_xor(sm, 2, 16);
      sm += __shfl_xor(sm, 4, 16);
      if (lr < 8) {
        float a = e / sm;
        anb[(wy * 64 + mt * 16 + lq * 4 + r) * 32 + lr] = f2bf(a);
      }
    }
  }
  __syncthreads();

  // upd = attn @ new_ss via K-padded MFMA, accumulate into x_v accs
  bf16x8 nf[4];
#pragma unroll
  for (int nt = 0; nt < 4; ++nt)
    nf[nt] = *(const bf16x8*)(nsl + (wx * 64 + nt * 16 + lr) * 32 + lq * 8);
#pragma unroll
  for (int mt = 0; mt < 4; ++mt) {
    bf16x8 afr = *(const bf16x8*)(anb + (wy * 64 + mt * 16 + lr) * 32 + lq * 8);
#pragma unroll
    for (int nt = 0; nt < 4; ++nt)
      acc[mt][nt] = __builtin_amdgcn_mfma_f32_16x16x32_bf16(
          afr, nf[nt], acc[mt][nt], 0, 0, 0);
  }

  float bvv[4];
#pragma unroll
  for (int nt = 0; nt < 4; ++nt) bvv[nt] = bv[n0 + wx * 64 + nt * 16 + lr];
#pragma unroll
  for (int mt = 0; mt < 4; ++mt) {
    int trow = wy * 64 + mt * 16 + lq * 4;
#pragma unroll
    for (int r = 0; r < 4; ++r) {
      int token = t0 + trow + r;
      if (token < TREG) {
        float* op = out + ((size_t)b * T_ + token) * D_ + n0 + wx * 64;
#pragma unroll
        for (int nt = 0; nt < 4; ++nt)
          op[nt * 16 + lr] = fmaxf(acc[mt][nt][r] + bvv[nt], 0.f);
      }
    }
  }
}

extern "C" void kernel_launch(void* const* d_in, const int* in_sizes, int n_in,
                              void* d_out, int out_size, void* d_ws, size_t ws_size,
                              hipStream_t stream) {
  (void)in_sizes; (void)n_in; (void)out_size;
  const float* x   = (const float*)d_in[0];
  const float* Wq  = (const float*)d_in[1];
  const float* bq  = (const float*)d_in[2];
  const float* Wk  = (const float*)d_in[3];
  const float* bk  = (const float*)d_in[4];
  const float* Wv  = (const float*)d_in[5];
  const float* bv  = (const float*)d_in[6];
  const float* Wss = (const float*)d_in[7];
  const float* bss = (const float*)d_in[8];
  float* out = (float*)d_out;

  const size_t SZ_XB   = (size_t)B_ * T_ * D_ * 2;        // 100663296
  const size_t SZ_WVT  = (size_t)D_ * D_ * 2;             // 1179648
  const size_t SZ_MEAN = (size_t)B_ * D_ * 4;             // 49152
  const size_t SZ_SSU  = (size_t)B_ * NK * 4;             // 98304
  const size_t SZ_NSSF = (size_t)B_ * NSS * D_ * 4;       // 393216
  const size_t SZ_NSST = (size_t)B_ * D_ * NSS * 2;       // 196608
  const size_t SZ_QB   = (size_t)B_ * NSS * 4;            // 512
  const size_t SZ_WQS  = (size_t)B_ * NSS * D_ * 2;       // 196608
  const size_t SMALL = SZ_WVT + SZ_MEAN + SZ_SSU + SZ_NSSF + SZ_NSST + SZ_QB + SZ_WQS;
  const size_t FULL = SZ_XB + SMALL;
  const bool big = ws_size >= FULL;

  char* ws = (char*)d_ws;
  size_t off = big ? SZ_XB : 0;
  u16*   xb    = (u16*)ws;
  u16*   wvT   = (u16*)(ws + off);   off += SZ_WVT;
  float* means = (float*)(ws + off); off += SZ_MEAN;
  float* ssu   = (float*)(ws + off); off += SZ_SSU;
  float* nssf  = (float*)(ws + off); off += SZ_NSSF;
  u16*   nssT  = (u16*)(ws + off);   off += SZ_NSST;
  float* qbb   = (float*)(ws + off); off += SZ_QB;
  u16*   wqsT  = (u16*)(ws + off);   off += SZ_WQS;

  hipMemsetAsync(means, 0, SZ_MEAN, stream);
  k_wvt<<<dim3(48, 48), 256, 0, stream>>>(Wv, wvT);
  if (big)
    k_conv_mean<true><<<dim3(128, 16), 192, 0, stream>>>(x, xb, means);
  else
    k_conv_mean<false><<<dim3(128, 16), 192, 0, stream>>>(x, nullptr, means);
  k_ssu<<<dim3(6, 16), 256, 0, stream>>>(means, Wk, bk, ssu);
  k_nss<<<dim3(NSS, 16), 256, 0, stream>>>(x, ssu, Wss, bss, bq, out, nssf, nssT, qbb);
  k_wqs<<<dim3(24, 16), 256, 0, stream>>>(Wq, nssf, wqsT);
  if (big)
    k_main<true><<<3072, 256, 0, stream>>>(xb, x, wvT, wqsT, nssT, qbb, bv, out);
  else
    k_main<false><<<3072, 256, 0, stream>>>(nullptr, x, wvT, wqsT, nssT, qbb, bv, out);
}

// Round 4
// 606.168 us; speedup vs baseline: 1.2499x; 1.2499x over previous
//
#include <hip/hip_runtime.h>
#include <hip/hip_bf16.h>

#define B_ 16
#define T_ 4096
#define TREG 4088
#define D_ 768
#define NSS 8
#define INNER_ 192
#define NK 1536
#define NCHUNK 128

typedef unsigned int u32;
typedef unsigned short u16;
typedef __attribute__((ext_vector_type(8))) short bf16x8;
typedef __attribute__((ext_vector_type(4))) float f32x4;

__device__ __forceinline__ u16 f2bf(float f) {
  union { __hip_bfloat16 h; u16 u; } cv;
  cv.h = __float2bfloat16(f);
  return cv.u;
}

// async global->LDS, 16B per lane. LDS dest is wave-uniform base + lane*16.
__device__ __forceinline__ void load16_lds(const void* g, void* l) {
  __builtin_amdgcn_global_load_lds(
      (const __attribute__((address_space(1))) u32*)(unsigned long long)g,
      (__attribute__((address_space(3))) u32*)(u32)(unsigned long long)l,
      16, 0, 0);
}

// ---------------- K0: Wv (768x768, k-major) -> WvT bf16 (n-major) ----------
__global__ __launch_bounds__(256) void k_wvt(const float* __restrict__ Wv,
                                             u16* __restrict__ wvT) {
  __shared__ float tile[16][17];
  int tx = threadIdx.x & 15, ty = threadIdx.x >> 4;
  int nb = blockIdx.x * 16, kb = blockIdx.y * 16;
  tile[ty][tx] = Wv[(size_t)(kb + ty) * D_ + nb + tx];
  __syncthreads();
  wvT[(size_t)(nb + ty) * D_ + kb + tx] = f2bf(tile[tx][ty]);
}

// ---------------- K1: cast x -> bf16 (optional) + per-batch partial sums ---
// grid (NCHUNK=128, B_), 192 thr; 32 tokens per block; NO atomics.
template <bool CONV>
__global__ __launch_bounds__(192) void k_conv_mean(const float* __restrict__ x,
                                                   u16* __restrict__ xb,
                                                   float* __restrict__ partials) {
  int b = blockIdx.y, tc = blockIdx.x, tid = threadIdx.x;
  const float4* xp = (const float4*)(x + (size_t)(b * T_ + tc * 32) * D_) + tid;
  ushort4* op = nullptr;
  if (CONV) op = ((ushort4*)(xb + (size_t)(b * T_ + tc * 32) * D_)) + tid;
  float s0 = 0, s1 = 0, s2 = 0, s3 = 0;
  int tbase = tc * 32;
#pragma unroll 4
  for (int tt = 0; tt < 32; ++tt) {
    float4 v = xp[(size_t)tt * 192];
    if (CONV) {
      ushort4 o;
      o.x = f2bf(v.x); o.y = f2bf(v.y); o.z = f2bf(v.z); o.w = f2bf(v.w);
      op[(size_t)tt * 192] = o;
    }
    if (tbase + tt < TREG) { s0 += v.x; s1 += v.y; s2 += v.z; s3 += v.w; }
  }
  float4 st; st.x = s0; st.y = s1; st.z = s2; st.w = s3;
  ((float4*)(partials + ((size_t)b * NCHUNK + tc) * D_))[tid] = st;
}

// ---------------- K2a: reduce partials -> mean; ssu = mean @ Wk + bk -------
__global__ __launch_bounds__(256) void k_ssu(const float* __restrict__ partials,
                                             const float* __restrict__ Wk,
                                             const float* __restrict__ bk,
                                             float* __restrict__ ssu) {
  int b = blockIdx.y, tid = threadIdx.x;
  int n = blockIdx.x * 256 + tid;
  __shared__ float mv[D_];
  for (int d = tid; d < D_; d += 256) {
    const float* p = partials + (size_t)b * NCHUNK * D_ + d;
    float s = 0;
#pragma unroll 8
    for (int c = 0; c < NCHUNK; ++c) s += p[(size_t)c * D_];
    mv[d] = s * (1.0f / TREG);
  }
  __syncthreads();
  float a = bk[n];
#pragma unroll 8
  for (int d = 0; d < D_; ++d) a += mv[d] * Wk[(size_t)d * NK + n];
  ssu[(size_t)b * NK + n] = a;
}

// ---------------- K2b: new_ss rows + qb; grid (NSS, B_) --------------------
__global__ __launch_bounds__(256) void k_nss(
    const float* __restrict__ x, const float* __restrict__ ssu,
    const float* __restrict__ Wss, const float* __restrict__ bss,
    const float* __restrict__ bq, float* __restrict__ out,
    float* __restrict__ nssf, u16* __restrict__ nssT, float* __restrict__ qb) {
  int s = blockIdx.x, b = blockIdx.y, tid = threadIdx.x;
  __shared__ float su[INNER_];
  __shared__ float qred[4];
  if (tid < INNER_) su[tid] = ssu[(size_t)b * NK + s * INNER_ + tid];
  __syncthreads();
  size_t xr = (size_t)(b * T_ + TREG + s) * D_;
  float a0 = x[xr + tid]       + bss[tid];
  float a1 = x[xr + tid + 256] + bss[tid + 256];
  float a2 = x[xr + tid + 512] + bss[tid + 512];
#pragma unroll 4
  for (int i = 0; i < INNER_; ++i) {
    float sv = su[i];
    const float* wr = Wss + (size_t)i * D_ + tid;
    a0 += sv * wr[0]; a1 += sv * wr[256]; a2 += sv * wr[512];
  }
  out[xr + tid] = a0; out[xr + tid + 256] = a1; out[xr + tid + 512] = a2;
  size_t nb = (size_t)(b * NSS + s) * D_;
  nssf[nb + tid] = a0; nssf[nb + tid + 256] = a1; nssf[nb + tid + 512] = a2;
  size_t tb = (size_t)b * D_;
  nssT[(tb + tid) * NSS + s] = f2bf(a0);
  nssT[(tb + tid + 256) * NSS + s] = f2bf(a1);
  nssT[(tb + tid + 512) * NSS + s] = f2bf(a2);
  float q = bq[tid] * a0 + bq[tid + 256] * a1 + bq[tid + 512] * a2;
#pragma unroll
  for (int o = 1; o < 64; o <<= 1) q += __shfl_xor(q, o, 64);
  if ((tid & 63) == 0) qred[tid >> 6] = q;
  __syncthreads();
  if (tid == 0) qb[b * NSS + s] = qred[0] + qred[1] + qred[2] + qred[3];
}

// ---------------- K2c: Wqs[b] = Wq @ new_ss[b]^T -> bf16 [b][8][768] -------
__global__ __launch_bounds__(256) void k_wqs(const float* __restrict__ Wq,
                                             const float* __restrict__ nssf,
                                             u16* __restrict__ wqsT) {
  __shared__ float nss[NSS * (D_ + 4)];
  int b = blockIdx.y, tid = threadIdx.x;
  int o = blockIdx.x * 256 + tid;
  int j = o >> 3, s = o & 7;
  for (int i = tid; i < NSS * D_; i += 256) {
    int s2 = i / D_, d2 = i - s2 * D_;
    nss[s2 * (D_ + 4) + d2] = nssf[(size_t)b * NSS * D_ + i];
  }
  __syncthreads();
  const float* wr = Wq + (size_t)j * D_;
  const float* nr = nss + s * (D_ + 4);
  float a = 0;
#pragma unroll 8
  for (int d = 0; d < D_; ++d) a += wr[d] * nr[d];
  wqsT[((size_t)b * NSS + s) * D_ + j] = f2bf(a);
}

// ---------------- K3: fused x_v GEMM + sim + softmax + upd + ReLU ----------
// Round-2 LDS global_load_lds pipeline (BK=32, single-buffered) + round-3
// XCD-swizzled 1D grid (each (t,b) A-tile owned by one XCD -> A read once)
// + __launch_bounds__(256,3) for 12 waves/CU.
template <bool ABF16>
__global__ __launch_bounds__(256, 3) void k_main(
    const u16* __restrict__ xb, const float* __restrict__ xf,
    const u16* __restrict__ wvT, const u16* __restrict__ wqsT,
    const u16* __restrict__ nssTg, const float* __restrict__ qb,
    const float* __restrict__ bv, float* __restrict__ out) {
  __shared__ uint4 ldsv[1800];                // 28800 B
  u16* lds = (u16*)ldsv;
  u16* As = lds;                               // 128x32 bf16 (8 KB)
  u16* Bs = lds + 4096;                        // 128x32 bf16 (8 KB)
  u16* Ws = lds + 8192;                        // Wqs: 8 rows x 776 (pad) bf16

  const int tid = threadIdx.x;
  // XCD-aware decode: g = xcd + 8*(pair*6 + nblk); pid = pair*8 + xcd.
  const int g = blockIdx.x;
  const int xcd = g & 7;
  const int li = g >> 3;            // 0..383
  const int nblk = li % 6;
  const int pair = li / 6;          // 0..63
  const int pid = pair * 8 + xcd;   // 0..511 unique (t,b)
  const int t0 = (pid & 31) * 128;
  const int b = pid >> 5;
  const int n0 = nblk * 128;

  const int wave = tid >> 6, lane = tid & 63;
  const int wy = wave >> 1, wx = wave & 1;
  const int lr = lane & 15, lq = lane >> 4;

  // stage Wqs rows (768 bf16 -> row stride 776 to dodge bank conflicts)
  if (tid < 96) {
    for (int s = 0; s < 8; ++s)
      ((uint4*)(Ws + s * 776))[tid] =
          ((const uint4*)(wqsT + ((size_t)b * NSS + s) * D_))[tid];
  }

  f32x4 acc[4][4];
  f32x4 sacc[4];
#pragma unroll
  for (int i = 0; i < 4; ++i) {
    sacc[i] = f32x4{0.f, 0.f, 0.f, 0.f};
#pragma unroll
    for (int j = 0; j < 4; ++j) acc[i][j] = f32x4{0.f, 0.f, 0.f, 0.f};
  }

  const u16* Bg = wvT + (size_t)n0 * D_;
  const int c1 = tid + 256;
  const int ar0 = tid >> 2, ak0 = (tid & 3) * 8;
  const int ar1 = c1 >> 2, ak1 = (c1 & 3) * 8;

  for (int k0 = 0; k0 < D_; k0 += 32) {
    if constexpr (ABF16) {
      const u16* Ag = xb + (size_t)(b * T_ + t0) * D_;
      load16_lds(Ag + (size_t)ar0 * D_ + k0 + ak0, As + tid * 8);
      load16_lds(Ag + (size_t)ar1 * D_ + k0 + ak1, As + c1 * 8);
    } else {
      const float* Af = xf + (size_t)(b * T_ + t0) * D_;
      const float* p0 = Af + (size_t)ar0 * D_ + k0 + ak0;
      const float* p1 = Af + (size_t)ar1 * D_ + k0 + ak1;
      float4 a0 = *(const float4*)p0, a1 = *(const float4*)(p0 + 4);
      float4 a2 = *(const float4*)p1, a3 = *(const float4*)(p1 + 4);
      ushort4 w0, w1, w2, w3;
      w0.x = f2bf(a0.x); w0.y = f2bf(a0.y); w0.z = f2bf(a0.z); w0.w = f2bf(a0.w);
      w1.x = f2bf(a1.x); w1.y = f2bf(a1.y); w1.z = f2bf(a1.z); w1.w = f2bf(a1.w);
      w2.x = f2bf(a2.x); w2.y = f2bf(a2.y); w2.z = f2bf(a2.z); w2.w = f2bf(a2.w);
      w3.x = f2bf(a3.x); w3.y = f2bf(a3.y); w3.z = f2bf(a3.z); w3.w = f2bf(a3.w);
      *(ushort4*)(As + tid * 8) = w0; *(ushort4*)(As + tid * 8 + 4) = w1;
      *(ushort4*)(As + c1 * 8) = w2; *(ushort4*)(As + c1 * 8 + 4) = w3;
    }
    load16_lds(Bg + (size_t)ar0 * D_ + k0 + ak0, Bs + tid * 8);
    load16_lds(Bg + (size_t)ar1 * D_ + k0 + ak1, Bs + c1 * 8);
    __syncthreads();

    bf16x8 af[4], bfr[4], qf;
#pragma unroll
    for (int mt = 0; mt < 4; ++mt)
      af[mt] = *(const bf16x8*)(As + (wy * 64 + mt * 16 + lr) * 32 + lq * 8);
#pragma unroll
    for (int nt = 0; nt < 4; ++nt)
      bfr[nt] = *(const bf16x8*)(Bs + (wx * 64 + nt * 16 + lr) * 32 + lq * 8);
    qf = *(const bf16x8*)(Ws + (lr & 7) * 776 + k0 + lq * 8);
#pragma unroll
    for (int mt = 0; mt < 4; ++mt) {
#pragma unroll
      for (int nt = 0; nt < 4; ++nt)
        acc[mt][nt] = __builtin_amdgcn_mfma_f32_16x16x32_bf16(
            af[mt], bfr[nt], acc[mt][nt], 0, 0, 0);
      sacc[mt] = __builtin_amdgcn_mfma_f32_16x16x32_bf16(
          af[mt], qf, sacc[mt], 0, 0, 0);
    }
    __syncthreads();
  }

  // ---- epilogue: overlay As->attnbuf(128x32), Bs->nssT(128x32), k<8 valid
  u16* anb = lds;
  u16* nsl = lds + 4096;
  {
    uint4 z; z.x = z.y = z.z = z.w = 0;
    if (tid < 128) {
      uint4 v = *(const uint4*)(nssTg + ((size_t)b * D_ + n0 + tid) * NSS);
      *(uint4*)(nsl + tid * 32) = v;
      *(uint4*)(nsl + tid * 32 + 8) = z;
      *(uint4*)(nsl + tid * 32 + 16) = z;
      *(uint4*)(nsl + tid * 32 + 24) = z;
    } else {
      int r = tid - 128;
      *(uint4*)(anb + r * 32 + 8) = z;
      *(uint4*)(anb + r * 32 + 16) = z;
      *(uint4*)(anb + r * 32 + 24) = z;
    }
  }
  __syncthreads();

  const float scale = 0.03608439182435161f;  // 1/sqrt(768)
  const float qbias = (lr < 8) ? qb[b * NSS + lr] : 0.f;
#pragma unroll
  for (int mt = 0; mt < 4; ++mt) {
    f32x4 s4 = sacc[mt];
#pragma unroll
    for (int r = 0; r < 4; ++r) {
      float v = (lr < 8) ? (s4[r] + qbias) * scale : -1.0e30f;
      float mx = v;
      mx = fmaxf(mx, __shfl_xor(mx, 1, 16));
      mx = fmaxf(mx, __shfl_xor(mx, 2, 16));
      mx = fmaxf(mx, __shfl_xor(mx, 4, 16));
      float e = (lr < 8) ? __expf(v - mx) : 0.f;
      float sm = e;
      sm += __shfl_xor(sm, 1, 16);
      sm += __shfl_xor(sm, 2, 16);
      sm += __shfl_xor(sm, 4, 16);
      if (lr < 8) {
        float a = e / sm;
        anb[(wy * 64 + mt * 16 + lq * 4 + r) * 32 + lr] = f2bf(a);
      }
    }
  }
  __syncthreads();

  // upd = attn @ new_ss via K-padded MFMA, accumulate into x_v accs
  bf16x8 nf[4];
#pragma unroll
  for (int nt = 0; nt < 4; ++nt)
    nf[nt] = *(const bf16x8*)(nsl + (wx * 64 + nt * 16 + lr) * 32 + lq * 8);
#pragma unroll
  for (int mt = 0; mt < 4; ++mt) {
    bf16x8 afr = *(const bf16x8*)(anb + (wy * 64 + mt * 16 + lr) * 32 + lq * 8);
#pragma unroll
    for (int nt = 0; nt < 4; ++nt)
      acc[mt][nt] = __builtin_amdgcn_mfma_f32_16x16x32_bf16(
          afr, nf[nt], acc[mt][nt], 0, 0, 0);
  }

  float bvv[4];
#pragma unroll
  for (int nt = 0; nt < 4; ++nt) bvv[nt] = bv[n0 + wx * 64 + nt * 16 + lr];
#pragma unroll
  for (int mt = 0; mt < 4; ++mt) {
    int trow = wy * 64 + mt * 16 + lq * 4;
#pragma unroll
    for (int r = 0; r < 4; ++r) {
      int token = t0 + trow + r;
      if (token < TREG) {
        float* op = out + ((size_t)b * T_ + token) * D_ + n0 + wx * 64;
#pragma unroll
        for (int nt = 0; nt < 4; ++nt)
          op[nt * 16 + lr] = fmaxf(acc[mt][nt][r] + bvv[nt], 0.f);
      }
    }
  }
}

extern "C" void kernel_launch(void* const* d_in, const int* in_sizes, int n_in,
                              void* d_out, int out_size, void* d_ws, size_t ws_size,
                              hipStream_t stream) {
  (void)in_sizes; (void)n_in; (void)out_size;
  const float* x   = (const float*)d_in[0];
  const float* Wq  = (const float*)d_in[1];
  const float* bq  = (const float*)d_in[2];
  const float* Wk  = (const float*)d_in[3];
  const float* bk  = (const float*)d_in[4];
  const float* Wv  = (const float*)d_in[5];
  const float* bv  = (const float*)d_in[6];
  const float* Wss = (const float*)d_in[7];
  const float* bss = (const float*)d_in[8];
  float* out = (float*)d_out;

  const size_t SZ_XB   = (size_t)B_ * T_ * D_ * 2;        // 100663296
  const size_t SZ_WVT  = (size_t)D_ * D_ * 2;             // 1179648
  const size_t SZ_PART = (size_t)B_ * NCHUNK * D_ * 4;    // 6291456
  const size_t SZ_SSU  = (size_t)B_ * NK * 4;             // 98304
  const size_t SZ_NSSF = (size_t)B_ * NSS * D_ * 4;       // 393216
  const size_t SZ_NSST = (size_t)B_ * D_ * NSS * 2;       // 196608
  const size_t SZ_QB   = (size_t)B_ * NSS * 4;            // 512
  const size_t SZ_WQS  = (size_t)B_ * NSS * D_ * 2;       // 196608
  const size_t SMALL = SZ_WVT + SZ_PART + SZ_SSU + SZ_NSSF + SZ_NSST + SZ_QB + SZ_WQS;
  const size_t FULL = SZ_XB + SMALL;
  const bool big = ws_size >= FULL;

  char* ws = (char*)d_ws;
  size_t off = big ? SZ_XB : 0;
  u16*   xb    = (u16*)ws;
  u16*   wvT   = (u16*)(ws + off);   off += SZ_WVT;
  float* parts = (float*)(ws + off); off += SZ_PART;
  float* ssu   = (float*)(ws + off); off += SZ_SSU;
  float* nssf  = (float*)(ws + off); off += SZ_NSSF;
  u16*   nssT  = (u16*)(ws + off);   off += SZ_NSST;
  float* qbb   = (float*)(ws + off); off += SZ_QB;
  u16*   wqsT  = (u16*)(ws + off);   off += SZ_WQS;

  k_wvt<<<dim3(48, 48), 256, 0, stream>>>(Wv, wvT);
  if (big)
    k_conv_mean<true><<<dim3(NCHUNK, 16), 192, 0, stream>>>(x, xb, parts);
  else
    k_conv_mean<false><<<dim3(NCHUNK, 16), 192, 0, stream>>>(x, nullptr, parts);
  k_ssu<<<dim3(6, 16), 256, 0, stream>>>(parts, Wk, bk, ssu);
  k_nss<<<dim3(NSS, 16), 256, 0, stream>>>(x, ssu, Wss, bss, bq, out, nssf, nssT, qbb);
  k_wqs<<<dim3(24, 16), 256, 0, stream>>>(Wq, nssf, wqsT);
  if (big)
    k_main<true><<<3072, 256, 0, stream>>>(xb, x, wvT, wqsT, nssT, qbb, bv, out);
  else
    k_main<false><<<3072, 256, 0, stream>>>(nullptr, x, wvT, wqsT, nssT, qbb, bv, out);
}